// Round 7
// baseline (307.786 us; speedup 1.0000x reference)
//
#include <hip/hip_runtime.h>
#include <hip/hip_bf16.h>
#include <cstddef>

#define DIMK 512
#define HEADS 8
#define DHEAD 64
#define NSEQ 2048
#define NB 8
#define M_TOT (NB * NSEQ)   // 16384

typedef __attribute__((ext_vector_type(8))) short bf16x8;
typedef __attribute__((ext_vector_type(4))) float f32x4;

__device__ __forceinline__ unsigned short f2bf(float f) {
    union { float f; unsigned int u; } v; v.f = f;
    unsigned int r = v.u + 0x7fffu + ((v.u >> 16) & 1u);   // round-nearest-even
    return (unsigned short)(r >> 16);
}

// pack two fp32 -> two trunc-bf16 in one dword: hi<<16 | lo  (1 VALU op)
__device__ __forceinline__ unsigned int pk_bf_trunc(float hi, float lo) {
    union { float f; unsigned int u; } a, b; a.f = hi; b.f = lo;
    return __builtin_amdgcn_perm(a.u, b.u, 0x07060302u);
}

// native 2^x (Q is pre-scaled by log2(e)*exp(log_scale) so this is the whole exp)
__device__ __forceinline__ float fexp2(float x) {
#if __has_builtin(__builtin_amdgcn_exp2f)
    return __builtin_amdgcn_exp2f(x);
#else
    return __expf(x * 0.69314718056f);
#endif
}

// async 16B/lane global->LDS. LDS dest is wave-uniform base + lane*16.
__device__ __forceinline__ void glds16(const unsigned short* g, unsigned short* l) {
    __builtin_amdgcn_global_load_lds(
        (const __attribute__((address_space(1))) void*)g,
        (__attribute__((address_space(3))) void*)l, 16, 0, 0);
}

// ---------------------------------------------------------------------------
// Pre-pass: x fp32 -> bf16 row-major [m][k]
// ---------------------------------------------------------------------------
__global__ __launch_bounds__(256) void f32_to_bf16(
    const float* __restrict__ in, unsigned short* __restrict__ out)
{
    const size_t i = ((size_t)blockIdx.x * 256 + threadIdx.x) * 8;
    const float4 a = *(const float4*)(in + i);
    const float4 b = *(const float4*)(in + i + 4);
    bf16x8 o;
    o[0] = (short)f2bf(a.x); o[1] = (short)f2bf(a.y);
    o[2] = (short)f2bf(a.z); o[3] = (short)f2bf(a.w);
    o[4] = (short)f2bf(b.x); o[5] = (short)f2bf(b.y);
    o[6] = (short)f2bf(b.z); o[7] = (short)f2bf(b.w);
    *(bf16x8*)(out + i) = o;
}

// ---------------------------------------------------------------------------
// Pre-pass (one launch): both weights K x N fp32 -> [N][512] bf16.
// Q-columns of w_qkv (n < 512) get *exp(log_scale)*log2(e) folded in.
// blocks x<48 -> w_qkv (N=1536); x>=48 -> w_out (N=512).
// ---------------------------------------------------------------------------
__global__ __launch_bounds__(256) void transpose_both(
    const float* __restrict__ w_qkv, const float* __restrict__ w_out,
    unsigned short* __restrict__ WqT, unsigned short* __restrict__ WoT,
    const float* __restrict__ log_scale)
{
    __shared__ float t[32][33];
    const int tx = threadIdx.x & 31, ty = threadIdx.x >> 5;
    const int k0 = blockIdx.y * 32;
    const float* W; unsigned short* WT; int N, n0;
    float sc = 1.0f;
    if (blockIdx.x < 48) {
        W = w_qkv; WT = WqT; N = 1536; n0 = blockIdx.x * 32;
        if (n0 < 512) sc = __expf(log_scale[0]) * 1.4426950408889634f;
    } else {
        W = w_out; WT = WoT; N = 512; n0 = (blockIdx.x - 48) * 32;
    }
    #pragma unroll
    for (int s = 0; s < 32; s += 8)
        t[ty + s][tx] = W[(size_t)(k0 + ty + s) * N + n0 + tx];
    __syncthreads();
    #pragma unroll
    for (int s = 0; s < 32; s += 8)
        WT[(size_t)(n0 + ty + s) * DIMK + k0 + tx] = f2bf(t[tx][ty + s] * sc);
}

// ---------------------------------------------------------------------------
// MFMA GEMM 1 (m97 structure). Grid (row-block, col-block) so linear%8 groups
// row-blocks per XCD (A-tile L2 locality). Epilogue scatters Q/K/V^T bf16.
// ---------------------------------------------------------------------------
__global__ __launch_bounds__(256) void gemm_qkv_mfma(
    const unsigned short* __restrict__ Xb, const unsigned short* __restrict__ WT,
    unsigned short* __restrict__ Qb, unsigned short* __restrict__ Kb,
    unsigned short* __restrict__ VTb)
{
    __shared__ unsigned short As[128 * 32];
    __shared__ unsigned short Bs[128 * 32];
    const int tid = threadIdx.x, wave = tid >> 6, lane = tid & 63;
    const int l16 = lane & 15, quad = lane >> 4;
    const int m0 = blockIdx.x * 128;          // row-block major for XCD locality
    const int cb = blockIdx.y;
    const int col0 = cb * 128;
    const int wrow = wave >> 1, wcol = wave & 1;

    unsigned short* lA0 = As + (wave * 16) * 32;
    unsigned short* lA1 = As + (64 + wave * 16) * 32;
    unsigned short* lB0 = Bs + (wave * 16) * 32;
    unsigned short* lB1 = Bs + (64 + wave * 16) * 32;
    const unsigned short* gA = Xb + (size_t)(m0 + wave * 16 + (lane >> 2)) * DIMK + (lane & 3) * 8;
    const unsigned short* gB = WT + (size_t)(col0 + wave * 16 + (lane >> 2)) * DIMK + (lane & 3) * 8;

    f32x4 acc[4][4];
    #pragma unroll
    for (int i = 0; i < 4; ++i)
        #pragma unroll
        for (int j = 0; j < 4; ++j) acc[i][j] = (f32x4){0.f, 0.f, 0.f, 0.f};

    for (int k0 = 0; k0 < DIMK; k0 += 32) {
        __syncthreads();
        glds16(gA + k0, lA0);
        glds16(gA + (size_t)64 * DIMK + k0, lA1);
        glds16(gB + k0, lB0);
        glds16(gB + (size_t)64 * DIMK + k0, lB1);
        __syncthreads();
        bf16x8 af[4], bfr[4];
        #pragma unroll
        for (int i = 0; i < 4; ++i)
            af[i] = *(const bf16x8*)(As + (wrow * 64 + i * 16 + l16) * 32 + quad * 8);
        #pragma unroll
        for (int j = 0; j < 4; ++j)
            bfr[j] = *(const bf16x8*)(Bs + (wcol * 64 + j * 16 + l16) * 32 + quad * 8);
        #pragma unroll
        for (int i = 0; i < 4; ++i)
            #pragma unroll
            for (int j = 0; j < 4; ++j)
                acc[i][j] = __builtin_amdgcn_mfma_f32_16x16x32_bf16(af[i], bfr[j], acc[i][j], 0, 0, 0);
    }

    const int which = cb >> 2;   // 0=Q 1=K 2=V, uniform per block
    #pragma unroll
    for (int i = 0; i < 4; ++i) {
        #pragma unroll
        for (int r = 0; r < 4; ++r) {
            const int gr = m0 + wrow * 64 + i * 16 + quad * 4 + r;
            const int bb = gr >> 11, n = gr & 2047;
            #pragma unroll
            for (int j = 0; j < 4; ++j) {
                const int col = col0 + wcol * 64 + j * 16 + l16;
                const int w = col & 511, h = w >> 6, d = w & 63;
                const size_t bh = (size_t)(bb * HEADS + h);
                const unsigned short val = f2bf(acc[i][j][r]);
                if (which == 0)      Qb[(bh * NSEQ + n) * DHEAD + d] = val;
                else if (which == 1) Kb[(bh * NSEQ + n) * DHEAD + d] = val;
                else                 VTb[(bh * DHEAD + d) * NSEQ + n] = val;
            }
        }
    }
}

// ---------------------------------------------------------------------------
// MFMA GEMM 2: out = O @ w_out + b_out (fp32 output). Row-block-major grid.
// ---------------------------------------------------------------------------
__global__ __launch_bounds__(256) void gemm_out_mfma(
    const unsigned short* __restrict__ Ab, const unsigned short* __restrict__ BT,
    const float* __restrict__ bias, float* __restrict__ C)
{
    __shared__ unsigned short As[128 * 32];
    __shared__ unsigned short Bs[128 * 32];
    const int tid = threadIdx.x, wave = tid >> 6, lane = tid & 63;
    const int l16 = lane & 15, quad = lane >> 4;
    const int m0 = blockIdx.x * 128, col0 = blockIdx.y * 128;
    const int wrow = wave >> 1, wcol = wave & 1;

    unsigned short* lA0 = As + (wave * 16) * 32;
    unsigned short* lA1 = As + (64 + wave * 16) * 32;
    unsigned short* lB0 = Bs + (wave * 16) * 32;
    unsigned short* lB1 = Bs + (64 + wave * 16) * 32;
    const unsigned short* gA = Ab + (size_t)(m0 + wave * 16 + (lane >> 2)) * DIMK + (lane & 3) * 8;
    const unsigned short* gB = BT + (size_t)(col0 + wave * 16 + (lane >> 2)) * DIMK + (lane & 3) * 8;

    f32x4 acc[4][4];
    #pragma unroll
    for (int i = 0; i < 4; ++i)
        #pragma unroll
        for (int j = 0; j < 4; ++j) acc[i][j] = (f32x4){0.f, 0.f, 0.f, 0.f};

    for (int k0 = 0; k0 < DIMK; k0 += 32) {
        __syncthreads();
        glds16(gA + k0, lA0);
        glds16(gA + (size_t)64 * DIMK + k0, lA1);
        glds16(gB + k0, lB0);
        glds16(gB + (size_t)64 * DIMK + k0, lB1);
        __syncthreads();
        bf16x8 af[4], bfr[4];
        #pragma unroll
        for (int i = 0; i < 4; ++i)
            af[i] = *(const bf16x8*)(As + (wrow * 64 + i * 16 + l16) * 32 + quad * 8);
        #pragma unroll
        for (int j = 0; j < 4; ++j)
            bfr[j] = *(const bf16x8*)(Bs + (wcol * 64 + j * 16 + l16) * 32 + quad * 8);
        #pragma unroll
        for (int i = 0; i < 4; ++i)
            #pragma unroll
            for (int j = 0; j < 4; ++j)
                acc[i][j] = __builtin_amdgcn_mfma_f32_16x16x32_bf16(af[i], bfr[j], acc[i][j], 0, 0, 0);
    }

    #pragma unroll
    for (int i = 0; i < 4; ++i) {
        #pragma unroll
        for (int r = 0; r < 4; ++r) {
            const int gr = m0 + wrow * 64 + i * 16 + quad * 4 + r;
            #pragma unroll
            for (int j = 0; j < 4; ++j) {
                const int col = col0 + wcol * 64 + j * 16 + l16;
                C[(size_t)gr * 512 + col] = acc[i][j][r] + bias[col];
            }
        }
    }
}

// ---------------------------------------------------------------------------
// Flash attention v5: K staged via glds (dbuf, 1 glds/wave/iter); V^T read
// DIRECTLY from global as dwordx4 A-fragments (L1/L2-served; waves in
// barrier-lockstep so fragments are shared in-cache). 128 q-rows/block
// (4 waves x 2 groups of 16), fixed-max exp2 softmax, row-sums via ones-MFMA,
// trunc-packed wave-private P, hoisted diag mask. LDS ~18 KB.
// Grid (bh=64, qtile=16): linear%8 == bh%8 pins each head-batch to one XCD.
// ---------------------------------------------------------------------------
__global__ __launch_bounds__(256) void attn_mfma(
    const unsigned short* __restrict__ Qb, const unsigned short* __restrict__ Kb,
    const unsigned short* __restrict__ VTb, unsigned short* __restrict__ O)
{
    __shared__ unsigned short Ks0[2][32 * 32];   // keys x d[0:32)
    __shared__ unsigned short Ks1[2][32 * 32];   // keys x d[32:64)
    __shared__ __align__(16) unsigned short Pq[4][2][16][40];  // per-wave/group P^T

    const int tid  = threadIdx.x;
    const int wave = tid >> 6;
    const int lane = tid & 63;
    const int l16  = lane & 15;
    const int quad = lane >> 4;
    const int bh   = blockIdx.x;               // XCD partition key
    const int q0   = blockIdx.y * 128;
    const int qwA  = q0 + wave * 16;
    const int qwB  = q0 + 64 + wave * 16;

    const unsigned short* Qg = Qb  + (size_t)bh * NSEQ * DHEAD;
    const unsigned short* Kg = Kb  + (size_t)bh * NSEQ * DHEAD;
    const unsigned short* Vg = VTb + (size_t)bh * DHEAD * NSEQ;

    // Q B-fragments for both groups, resident all kernel
    const bf16x8 b_qA0 = *(const bf16x8*)(Qg + (size_t)(qwA + l16) * DHEAD + quad * 8);
    const bf16x8 b_qA1 = *(const bf16x8*)(Qg + (size_t)(qwA + l16) * DHEAD + 32 + quad * 8);
    const bf16x8 b_qB0 = *(const bf16x8*)(Qg + (size_t)(qwB + l16) * DHEAD + quad * 8);
    const bf16x8 b_qB1 = *(const bf16x8*)(Qg + (size_t)(qwB + l16) * DHEAD + 32 + quad * 8);

    // constant all-ones A fragment: row-sum of P via the matrix pipe
    bf16x8 a_ones;
    #pragma unroll
    for (int i = 0; i < 8; ++i) a_ones[i] = (short)0x3F80;   // bf16 1.0

    // K staging: 1 glds16 per wave per tile. wave&1 -> 16-row half,
    // wave>>1 -> d-half (Ks0: d[0:32), Ks1: d[32:64)).
    const int r16 = lane >> 2, c8 = (lane & 3) * 8;
    const unsigned short* srcK =
        Kg + (size_t)((wave & 1) * 16 + r16) * DHEAD + (wave >> 1) * 32 + c8;
    unsigned short* dK[2];
    dK[0] = ((wave >> 1) ? &Ks1[0][0] : &Ks0[0][0]) + (wave & 1) * 512;
    dK[1] = ((wave >> 1) ? &Ks1[1][0] : &Ks0[1][0]) + (wave & 1) * 512;

    f32x4 oA[4], oB[4], laccA, laccB;
    #pragma unroll
    for (int t = 0; t < 4; ++t) { oA[t] = (f32x4){0.f,0.f,0.f,0.f}; oB[t] = (f32x4){0.f,0.f,0.f,0.f}; }
    laccA = (f32x4){0.f,0.f,0.f,0.f};
    laccB = (f32x4){0.f,0.f,0.f,0.f};

    // prologue: stage tile 0 into buffer 0
    glds16(srcK, dK[0]);
    srcK += (size_t)32 * DHEAD;

    for (int it = 0; it < NSEQ / 32; ++it) {
        const int cur = it & 1;
        const int j0  = it * 32;
        __syncthreads();   // buffer `cur` staged; everyone done with `cur^1`

        if (it < NSEQ / 32 - 1) {   // prefetch next K tile into the other buffer
            glds16(srcK, dK[cur ^ 1]);
            srcK += (size_t)32 * DHEAD;
        }

        // ---- V^T fragments straight from global (L1/L2); issued early ----
        bf16x8 vfrag[4];
        #pragma unroll
        for (int t = 0; t < 4; ++t)
            vfrag[t] = *(const bf16x8*)(Vg + (size_t)(t * 16 + l16) * NSEQ + j0 + quad * 8);

        // ---- S^T = K Q^T (2 m-tiles of 16 keys); p = exp2(s); diag mask ----
        float pA[2][4], pB[2][4];
        #pragma unroll
        for (int t = 0; t < 2; ++t) {
            const bf16x8 a0 = *(const bf16x8*)(&Ks0[cur][(t * 16 + l16) * 32 + quad * 8]);
            const bf16x8 a1 = *(const bf16x8*)(&Ks1[cur][(t * 16 + l16) * 32 + quad * 8]);
            f32x4 sA = (f32x4){0.f,0.f,0.f,0.f}, sB = (f32x4){0.f,0.f,0.f,0.f};
            sA = __builtin_amdgcn_mfma_f32_16x16x32_bf16(a0, b_qA0, sA, 0, 0, 0);
            sA = __builtin_amdgcn_mfma_f32_16x16x32_bf16(a1, b_qA1, sA, 0, 0, 0);
            sB = __builtin_amdgcn_mfma_f32_16x16x32_bf16(a0, b_qB0, sB, 0, 0, 0);
            sB = __builtin_amdgcn_mfma_f32_16x16x32_bf16(a1, b_qB1, sB, 0, 0, 0);
            #pragma unroll
            for (int r = 0; r < 4; ++r) { pA[t][r] = fexp2(sA[r]); pB[t][r] = fexp2(sB[r]); }
            if (j0 + 16 * t == qwA) {   // wave-uniform
                #pragma unroll
                for (int r = 0; r < 4; ++r) if (l16 == quad * 4 + r) pA[t][r] = 0.f;
            }
            if (j0 + 16 * t == qwB) {
                #pragma unroll
                for (int r = 0; r < 4; ++r) if (l16 == quad * 4 + r) pB[t][r] = 0.f;
            }
        }

        // ---- pack P^T (trunc bf16) into wave-private LDS ----
        #pragma unroll
        for (int t = 0; t < 2; ++t) {
            uint2 wA, wB;
            wA.x = pk_bf_trunc(pA[t][1], pA[t][0]); wA.y = pk_bf_trunc(pA[t][3], pA[t][2]);
            wB.x = pk_bf_trunc(pB[t][1], pB[t][0]); wB.y = pk_bf_trunc(pB[t][3], pB[t][2]);
            *(uint2*)(&Pq[wave][0][l16][t * 16 + quad * 4]) = wA;
            *(uint2*)(&Pq[wave][1][l16][t * 16 + quad * 4]) = wB;
        }
        __builtin_amdgcn_wave_barrier();   // wave-private round-trip

        const bf16x8 b_pA = *(const bf16x8*)(&Pq[wave][0][l16][quad * 8]);
        const bf16x8 b_pB = *(const bf16x8*)(&Pq[wave][1][l16][quad * 8]);

        // ---- row-sums via ones-MFMA; O^T += V^T P^T ----
        laccA = __builtin_amdgcn_mfma_f32_16x16x32_bf16(a_ones, b_pA, laccA, 0, 0, 0);
        laccB = __builtin_amdgcn_mfma_f32_16x16x32_bf16(a_ones, b_pB, laccB, 0, 0, 0);
        #pragma unroll
        for (int t = 0; t < 4; ++t) {
            oA[t] = __builtin_amdgcn_mfma_f32_16x16x32_bf16(vfrag[t], b_pA, oA[t], 0, 0, 0);
            oB[t] = __builtin_amdgcn_mfma_f32_16x16x32_bf16(vfrag[t], b_pB, oB[t], 0, 0, 0);
        }
    }

    // ---- epilogue: l is per-lane in every acc reg ----
    const float invA = 1.0f / laccA[0];
    const float invB = 1.0f / laccB[0];
    const int bb = bh >> 3, h = bh & 7;
    {
        const int n = qwA + l16;
        unsigned short* Orow = O + ((size_t)(bb * NSEQ + n)) * 512 + h * 64;
        #pragma unroll
        for (int t = 0; t < 4; ++t) {
            ushort4 o4;
            o4.x = f2bf(oA[t][0] * invA); o4.y = f2bf(oA[t][1] * invA);
            o4.z = f2bf(oA[t][2] * invA); o4.w = f2bf(oA[t][3] * invA);
            *(ushort4*)(Orow + t * 16 + quad * 4) = o4;
        }
    }
    {
        const int n = qwB + l16;
        unsigned short* Orow = O + ((size_t)(bb * NSEQ + n)) * 512 + h * 64;
        #pragma unroll
        for (int t = 0; t < 4; ++t) {
            ushort4 o4;
            o4.x = f2bf(oB[t][0] * invB); o4.y = f2bf(oB[t][1] * invB);
            o4.z = f2bf(oB[t][2] * invB); o4.w = f2bf(oB[t][3] * invB);
            *(ushort4*)(Orow + t * 16 + quad * 4) = o4;
        }
    }
}

extern "C" void kernel_launch(void* const* d_in, const int* in_sizes, int n_in,
                              void* d_out, int out_size, void* d_ws, size_t ws_size,
                              hipStream_t stream) {
    const float* x         = (const float*)d_in[0];
    const float* w_qkv     = (const float*)d_in[1];
    const float* w_out     = (const float*)d_in[2];
    const float* b_out     = (const float*)d_in[3];
    const float* log_scale = (const float*)d_in[4];
    float* out = (float*)d_out;

    char* ws = (char*)d_ws;
    const size_t NQKV = (size_t)NB * HEADS * NSEQ * DHEAD;        // 8,388,608 elems
    unsigned short* xb  = (unsigned short*)(ws);
    unsigned short* Qb  = (unsigned short*)(ws + 2 * NQKV);
    unsigned short* Kb  = (unsigned short*)(ws + 4 * NQKV);
    unsigned short* VTb = (unsigned short*)(ws + 6 * NQKV);
    unsigned short* Ofb = (unsigned short*)(ws + 8 * NQKV);
    unsigned short* WqT = (unsigned short*)(ws + 10 * NQKV);
    unsigned short* WoT = (unsigned short*)(ws + 10 * NQKV + 4 * 1024 * 1024);

    f32_to_bf16<<<M_TOT * DIMK / (256 * 8), 256, 0, stream>>>(x, xb);
    transpose_both<<<dim3(64, 16), 256, 0, stream>>>(w_qkv, w_out, WqT, WoT, log_scale);

    gemm_qkv_mfma<<<dim3(M_TOT / 128, 1536 / 128), 256, 0, stream>>>(xb, WqT, Qb, Kb, VTb);

    attn_mfma<<<dim3(NB * HEADS, NSEQ / 128), 256, 0, stream>>>(Qb, Kb, VTb, Ofb);

    gemm_out_mfma<<<dim3(M_TOT / 128, 512 / 128), 256, 0, stream>>>(Ofb, WoT, b_out, out);
}

// Round 8
// 259.552 us; speedup vs baseline: 1.1858x; 1.1858x over previous
//
#include <hip/hip_runtime.h>
#include <hip/hip_bf16.h>
#include <cstddef>

#define DIMK 512
#define HEADS 8
#define DHEAD 64
#define NSEQ 2048
#define NB 8
#define M_TOT (NB * NSEQ)   // 16384

typedef __attribute__((ext_vector_type(8))) short bf16x8;
typedef __attribute__((ext_vector_type(4))) float f32x4;

__device__ __forceinline__ unsigned short f2bf(float f) {
    union { float f; unsigned int u; } v; v.f = f;
    unsigned int r = v.u + 0x7fffu + ((v.u >> 16) & 1u);   // round-nearest-even
    return (unsigned short)(r >> 16);
}

// pack two fp32 -> two trunc-bf16 in one dword: hi<<16 | lo  (1 VALU op)
__device__ __forceinline__ unsigned int pk_bf_trunc(float hi, float lo) {
    union { float f; unsigned int u; } a, b; a.f = hi; b.f = lo;
    return __builtin_amdgcn_perm(a.u, b.u, 0x07060302u);
}

// native 2^x (Q is pre-scaled by log2(e)*exp(log_scale) so this is the whole exp)
__device__ __forceinline__ float fexp2(float x) {
#if __has_builtin(__builtin_amdgcn_exp2f)
    return __builtin_amdgcn_exp2f(x);
#else
    return __expf(x * 0.69314718056f);
#endif
}

// async 16B/lane global->LDS. LDS dest is wave-uniform base + lane*16.
__device__ __forceinline__ void glds16(const unsigned short* g, unsigned short* l) {
    __builtin_amdgcn_global_load_lds(
        (const __attribute__((address_space(1))) void*)g,
        (__attribute__((address_space(3))) void*)l, 16, 0, 0);
}

// ---------------------------------------------------------------------------
// Pre-pass: x fp32 -> bf16 row-major [m][k]
// ---------------------------------------------------------------------------
__global__ __launch_bounds__(256) void f32_to_bf16(
    const float* __restrict__ in, unsigned short* __restrict__ out)
{
    const size_t i = ((size_t)blockIdx.x * 256 + threadIdx.x) * 8;
    const float4 a = *(const float4*)(in + i);
    const float4 b = *(const float4*)(in + i + 4);
    bf16x8 o;
    o[0] = (short)f2bf(a.x); o[1] = (short)f2bf(a.y);
    o[2] = (short)f2bf(a.z); o[3] = (short)f2bf(a.w);
    o[4] = (short)f2bf(b.x); o[5] = (short)f2bf(b.y);
    o[6] = (short)f2bf(b.z); o[7] = (short)f2bf(b.w);
    *(bf16x8*)(out + i) = o;
}

// ---------------------------------------------------------------------------
// Pre-pass (one launch): both weights K x N fp32 -> [N][512] bf16.
// Q-columns of w_qkv (n < 512) get *exp(log_scale)*log2(e) folded in.
// blocks x<48 -> w_qkv (N=1536); x>=48 -> w_out (N=512).
// ---------------------------------------------------------------------------
__global__ __launch_bounds__(256) void transpose_both(
    const float* __restrict__ w_qkv, const float* __restrict__ w_out,
    unsigned short* __restrict__ WqT, unsigned short* __restrict__ WoT,
    const float* __restrict__ log_scale)
{
    __shared__ float t[32][33];
    const int tx = threadIdx.x & 31, ty = threadIdx.x >> 5;
    const int k0 = blockIdx.y * 32;
    const float* W; unsigned short* WT; int N, n0;
    float sc = 1.0f;
    if (blockIdx.x < 48) {
        W = w_qkv; WT = WqT; N = 1536; n0 = blockIdx.x * 32;
        if (n0 < 512) sc = __expf(log_scale[0]) * 1.4426950408889634f;
    } else {
        W = w_out; WT = WoT; N = 512; n0 = (blockIdx.x - 48) * 32;
    }
    #pragma unroll
    for (int s = 0; s < 32; s += 8)
        t[ty + s][tx] = W[(size_t)(k0 + ty + s) * N + n0 + tx];
    __syncthreads();
    #pragma unroll
    for (int s = 0; s < 32; s += 8)
        WT[(size_t)(n0 + ty + s) * DIMK + k0 + tx] = f2bf(t[tx][ty + s] * sc);
}

// ---------------------------------------------------------------------------
// MFMA GEMM 1 (m97 structure), row-block-major grid for XCD A-tile locality.
// Epilogue scatters Q (scales folded), K, V^T bf16.
// ---------------------------------------------------------------------------
__global__ __launch_bounds__(256) void gemm_qkv_mfma(
    const unsigned short* __restrict__ Xb, const unsigned short* __restrict__ WT,
    unsigned short* __restrict__ Qb, unsigned short* __restrict__ Kb,
    unsigned short* __restrict__ VTb)
{
    __shared__ unsigned short As[128 * 32];
    __shared__ unsigned short Bs[128 * 32];
    const int tid = threadIdx.x, wave = tid >> 6, lane = tid & 63;
    const int l16 = lane & 15, quad = lane >> 4;
    const int m0 = blockIdx.x * 128;
    const int cb = blockIdx.y;
    const int col0 = cb * 128;
    const int wrow = wave >> 1, wcol = wave & 1;

    unsigned short* lA0 = As + (wave * 16) * 32;
    unsigned short* lA1 = As + (64 + wave * 16) * 32;
    unsigned short* lB0 = Bs + (wave * 16) * 32;
    unsigned short* lB1 = Bs + (64 + wave * 16) * 32;
    const unsigned short* gA = Xb + (size_t)(m0 + wave * 16 + (lane >> 2)) * DIMK + (lane & 3) * 8;
    const unsigned short* gB = WT + (size_t)(col0 + wave * 16 + (lane >> 2)) * DIMK + (lane & 3) * 8;

    f32x4 acc[4][4];
    #pragma unroll
    for (int i = 0; i < 4; ++i)
        #pragma unroll
        for (int j = 0; j < 4; ++j) acc[i][j] = (f32x4){0.f, 0.f, 0.f, 0.f};

    for (int k0 = 0; k0 < DIMK; k0 += 32) {
        __syncthreads();
        glds16(gA + k0, lA0);
        glds16(gA + (size_t)64 * DIMK + k0, lA1);
        glds16(gB + k0, lB0);
        glds16(gB + (size_t)64 * DIMK + k0, lB1);
        __syncthreads();
        bf16x8 af[4], bfr[4];
        #pragma unroll
        for (int i = 0; i < 4; ++i)
            af[i] = *(const bf16x8*)(As + (wrow * 64 + i * 16 + l16) * 32 + quad * 8);
        #pragma unroll
        for (int j = 0; j < 4; ++j)
            bfr[j] = *(const bf16x8*)(Bs + (wcol * 64 + j * 16 + l16) * 32 + quad * 8);
        #pragma unroll
        for (int i = 0; i < 4; ++i)
            #pragma unroll
            for (int j = 0; j < 4; ++j)
                acc[i][j] = __builtin_amdgcn_mfma_f32_16x16x32_bf16(af[i], bfr[j], acc[i][j], 0, 0, 0);
    }

    const int which = cb >> 2;   // 0=Q 1=K 2=V, uniform per block
    #pragma unroll
    for (int i = 0; i < 4; ++i) {
        #pragma unroll
        for (int r = 0; r < 4; ++r) {
            const int gr = m0 + wrow * 64 + i * 16 + quad * 4 + r;
            const int bb = gr >> 11, n = gr & 2047;
            #pragma unroll
            for (int j = 0; j < 4; ++j) {
                const int col = col0 + wcol * 64 + j * 16 + l16;
                const int w = col & 511, h = w >> 6, d = w & 63;
                const size_t bh = (size_t)(bb * HEADS + h);
                const unsigned short val = f2bf(acc[i][j][r]);
                if (which == 0)      Qb[(bh * NSEQ + n) * DHEAD + d] = val;
                else if (which == 1) Kb[(bh * NSEQ + n) * DHEAD + d] = val;
                else                 VTb[(bh * DHEAD + d) * NSEQ + n] = val;
            }
        }
    }
}

// ---------------------------------------------------------------------------
// MFMA GEMM 2: out = O @ w_out + b_out (fp32 output). Row-block-major grid.
// ---------------------------------------------------------------------------
__global__ __launch_bounds__(256) void gemm_out_mfma(
    const unsigned short* __restrict__ Ab, const unsigned short* __restrict__ BT,
    const float* __restrict__ bias, float* __restrict__ C)
{
    __shared__ unsigned short As[128 * 32];
    __shared__ unsigned short Bs[128 * 32];
    const int tid = threadIdx.x, wave = tid >> 6, lane = tid & 63;
    const int l16 = lane & 15, quad = lane >> 4;
    const int m0 = blockIdx.x * 128, col0 = blockIdx.y * 128;
    const int wrow = wave >> 1, wcol = wave & 1;

    unsigned short* lA0 = As + (wave * 16) * 32;
    unsigned short* lA1 = As + (64 + wave * 16) * 32;
    unsigned short* lB0 = Bs + (wave * 16) * 32;
    unsigned short* lB1 = Bs + (64 + wave * 16) * 32;
    const unsigned short* gA = Ab + (size_t)(m0 + wave * 16 + (lane >> 2)) * DIMK + (lane & 3) * 8;
    const unsigned short* gB = BT + (size_t)(col0 + wave * 16 + (lane >> 2)) * DIMK + (lane & 3) * 8;

    f32x4 acc[4][4];
    #pragma unroll
    for (int i = 0; i < 4; ++i)
        #pragma unroll
        for (int j = 0; j < 4; ++j) acc[i][j] = (f32x4){0.f, 0.f, 0.f, 0.f};

    for (int k0 = 0; k0 < DIMK; k0 += 32) {
        __syncthreads();
        glds16(gA + k0, lA0);
        glds16(gA + (size_t)64 * DIMK + k0, lA1);
        glds16(gB + k0, lB0);
        glds16(gB + (size_t)64 * DIMK + k0, lB1);
        __syncthreads();
        bf16x8 af[4], bfr[4];
        #pragma unroll
        for (int i = 0; i < 4; ++i)
            af[i] = *(const bf16x8*)(As + (wrow * 64 + i * 16 + l16) * 32 + quad * 8);
        #pragma unroll
        for (int j = 0; j < 4; ++j)
            bfr[j] = *(const bf16x8*)(Bs + (wcol * 64 + j * 16 + l16) * 32 + quad * 8);
        #pragma unroll
        for (int i = 0; i < 4; ++i)
            #pragma unroll
            for (int j = 0; j < 4; ++j)
                acc[i][j] = __builtin_amdgcn_mfma_f32_16x16x32_bf16(af[i], bfr[j], acc[i][j], 0, 0, 0);
    }

    #pragma unroll
    for (int i = 0; i < 4; ++i) {
        #pragma unroll
        for (int r = 0; r < 4; ++r) {
            const int gr = m0 + wrow * 64 + i * 16 + quad * 4 + r;
            #pragma unroll
            for (int j = 0; j < 4; ++j) {
                const int col = col0 + wcol * 64 + j * 16 + l16;
                C[(size_t)gr * 512 + col] = acc[i][j][r] + bias[col];
            }
        }
    }
}

// ---------------------------------------------------------------------------
// Flash attention v6 = R6 body + XCD-pinned grid.
// 32-key double-buffered glds tiles for K AND V^T (all operand reads on the
// LDS pipe — R7 showed direct global V-frags serialize against the prefetch
// via in-order vmcnt). 128 q-rows/block (4 waves x 2 groups), fixed-max exp2
// softmax, row-sums via ones-MFMA, trunc-packed wave-private P, hoisted diag
// mask, one barrier per tile. LDS ~26 KB -> 4 blocks/CU (grid-capped).
// Grid (bh=64, qtile=16): linear%8 == bh%8 pins each head-batch to one XCD;
// that XCD's L2 then holds exactly its 8 heads' K/V (4 MB). FETCH ~41 MB.
// ---------------------------------------------------------------------------
__global__ __launch_bounds__(256) void attn_mfma(
    const unsigned short* __restrict__ Qb, const unsigned short* __restrict__ Kb,
    const unsigned short* __restrict__ VTb, unsigned short* __restrict__ O)
{
    __shared__ unsigned short Ks0[2][32 * 32];   // keys x d[0:32)
    __shared__ unsigned short Ks1[2][32 * 32];   // keys x d[32:64)
    __shared__ unsigned short Vs[2][64 * 32];    // d x keys[0:32)
    __shared__ __align__(16) unsigned short Pq[4][2][16][40];  // per-wave/group P^T

    const int tid  = threadIdx.x;
    const int wave = tid >> 6;
    const int lane = tid & 63;
    const int l16  = lane & 15;
    const int quad = lane >> 4;
    const int bh   = blockIdx.x;               // XCD partition key
    const int q0   = blockIdx.y * 128;
    const int qwA  = q0 + wave * 16;
    const int qwB  = q0 + 64 + wave * 16;

    const unsigned short* Qg = Qb  + (size_t)bh * NSEQ * DHEAD;
    const unsigned short* Kg = Kb  + (size_t)bh * NSEQ * DHEAD;
    const unsigned short* Vg = VTb + (size_t)bh * DHEAD * NSEQ;

    // Q B-fragments for both groups, resident all kernel
    const bf16x8 b_qA0 = *(const bf16x8*)(Qg + (size_t)(qwA + l16) * DHEAD + quad * 8);
    const bf16x8 b_qA1 = *(const bf16x8*)(Qg + (size_t)(qwA + l16) * DHEAD + 32 + quad * 8);
    const bf16x8 b_qB0 = *(const bf16x8*)(Qg + (size_t)(qwB + l16) * DHEAD + quad * 8);
    const bf16x8 b_qB1 = *(const bf16x8*)(Qg + (size_t)(qwB + l16) * DHEAD + 32 + quad * 8);

    // constant all-ones A fragment: row-sum of P via the matrix pipe
    bf16x8 a_ones;
    #pragma unroll
    for (int i = 0; i < 8; ++i) a_ones[i] = (short)0x3F80;   // bf16 1.0

    // staging roles (wave-uniform): wave0 Ks0, wave1 Ks1, wave2/3 Vs halves
    const int r16 = lane >> 2;            // 0..15
    const int c8  = (lane & 3) * 8;       // 0,8,16,24
    const unsigned short* src0;
    const unsigned short* src1;
    size_t step;
    unsigned short* dA[2];
    unsigned short* dB[2];
    if (wave == 0) {
        src0 = Kg + (size_t)r16 * DHEAD + c8;           src1 = src0 + 16 * DHEAD;
        step = 32 * DHEAD;
        dA[0] = &Ks0[0][0];  dA[1] = &Ks0[1][0];
        dB[0] = &Ks0[0][512]; dB[1] = &Ks0[1][512];
    } else if (wave == 1) {
        src0 = Kg + (size_t)r16 * DHEAD + 32 + c8;      src1 = src0 + 16 * DHEAD;
        step = 32 * DHEAD;
        dA[0] = &Ks1[0][0];  dA[1] = &Ks1[1][0];
        dB[0] = &Ks1[0][512]; dB[1] = &Ks1[1][512];
    } else if (wave == 2) {
        src0 = Vg + (size_t)r16 * NSEQ + c8;            src1 = src0 + (size_t)16 * NSEQ;
        step = 32;
        dA[0] = &Vs[0][0];   dA[1] = &Vs[1][0];
        dB[0] = &Vs[0][512]; dB[1] = &Vs[1][512];
    } else {
        src0 = Vg + (size_t)(32 + r16) * NSEQ + c8;     src1 = src0 + (size_t)16 * NSEQ;
        step = 32;
        dA[0] = &Vs[0][1024]; dA[1] = &Vs[1][1024];
        dB[0] = &Vs[0][1536]; dB[1] = &Vs[1][1536];
    }

    f32x4 oA[4], oB[4], laccA, laccB;
    #pragma unroll
    for (int t = 0; t < 4; ++t) { oA[t] = (f32x4){0.f,0.f,0.f,0.f}; oB[t] = (f32x4){0.f,0.f,0.f,0.f}; }
    laccA = (f32x4){0.f,0.f,0.f,0.f};
    laccB = (f32x4){0.f,0.f,0.f,0.f};

    // prologue: stage tile 0 into buffer 0
    glds16(src0, dA[0]);
    glds16(src1, dB[0]);
    src0 += step; src1 += step;

    #pragma unroll 2
    for (int it = 0; it < NSEQ / 32; ++it) {
        const int cur = it & 1;
        const int j0  = it * 32;
        __syncthreads();   // buffer `cur` staged; everyone done with `cur^1`

        if (it < NSEQ / 32 - 1) {   // prefetch next tile into the other buffer
            glds16(src0, dA[cur ^ 1]);
            glds16(src1, dB[cur ^ 1]);
            src0 += step; src1 += step;
        }

        // ---- S^T = K Q^T (2 m-tiles of 16 keys); p = exp2(s); diag mask ----
        float pA[2][4], pB[2][4];
        #pragma unroll
        for (int t = 0; t < 2; ++t) {
            const bf16x8 a0 = *(const bf16x8*)(&Ks0[cur][(t * 16 + l16) * 32 + quad * 8]);
            const bf16x8 a1 = *(const bf16x8*)(&Ks1[cur][(t * 16 + l16) * 32 + quad * 8]);
            f32x4 sA = (f32x4){0.f,0.f,0.f,0.f}, sB = (f32x4){0.f,0.f,0.f,0.f};
            sA = __builtin_amdgcn_mfma_f32_16x16x32_bf16(a0, b_qA0, sA, 0, 0, 0);
            sA = __builtin_amdgcn_mfma_f32_16x16x32_bf16(a1, b_qA1, sA, 0, 0, 0);
            sB = __builtin_amdgcn_mfma_f32_16x16x32_bf16(a0, b_qB0, sB, 0, 0, 0);
            sB = __builtin_amdgcn_mfma_f32_16x16x32_bf16(a1, b_qB1, sB, 0, 0, 0);
            #pragma unroll
            for (int r = 0; r < 4; ++r) { pA[t][r] = fexp2(sA[r]); pB[t][r] = fexp2(sB[r]); }
            if (j0 + 16 * t == qwA) {   // wave-uniform
                #pragma unroll
                for (int r = 0; r < 4; ++r) if (l16 == quad * 4 + r) pA[t][r] = 0.f;
            }
            if (j0 + 16 * t == qwB) {
                #pragma unroll
                for (int r = 0; r < 4; ++r) if (l16 == quad * 4 + r) pB[t][r] = 0.f;
            }
        }

        // ---- pack P^T (trunc bf16) into wave-private LDS ----
        #pragma unroll
        for (int t = 0; t < 2; ++t) {
            uint2 wA, wB;
            wA.x = pk_bf_trunc(pA[t][1], pA[t][0]); wA.y = pk_bf_trunc(pA[t][3], pA[t][2]);
            wB.x = pk_bf_trunc(pB[t][1], pB[t][0]); wB.y = pk_bf_trunc(pB[t][3], pB[t][2]);
            *(uint2*)(&Pq[wave][0][l16][t * 16 + quad * 4]) = wA;
            *(uint2*)(&Pq[wave][1][l16][t * 16 + quad * 4]) = wB;
        }
        __builtin_amdgcn_wave_barrier();   // wave-private round-trip

        const bf16x8 b_pA = *(const bf16x8*)(&Pq[wave][0][l16][quad * 8]);
        const bf16x8 b_pB = *(const bf16x8*)(&Pq[wave][1][l16][quad * 8]);

        // ---- row-sums via ones-MFMA; O^T += V^T P^T ----
        laccA = __builtin_amdgcn_mfma_f32_16x16x32_bf16(a_ones, b_pA, laccA, 0, 0, 0);
        laccB = __builtin_amdgcn_mfma_f32_16x16x32_bf16(a_ones, b_pB, laccB, 0, 0, 0);
        #pragma unroll
        for (int t = 0; t < 4; ++t) {
            const bf16x8 v = *(const bf16x8*)(&Vs[cur][(t * 16 + l16) * 32 + quad * 8]);
            oA[t] = __builtin_amdgcn_mfma_f32_16x16x32_bf16(v, b_pA, oA[t], 0, 0, 0);
            oB[t] = __builtin_amdgcn_mfma_f32_16x16x32_bf16(v, b_pB, oB[t], 0, 0, 0);
        }
    }

    // ---- epilogue: l is per-lane in every acc reg ----
    const float invA = 1.0f / laccA[0];
    const float invB = 1.0f / laccB[0];
    const int bb = bh >> 3, h = bh & 7;
    {
        const int n = qwA + l16;
        unsigned short* Orow = O + ((size_t)(bb * NSEQ + n)) * 512 + h * 64;
        #pragma unroll
        for (int t = 0; t < 4; ++t) {
            ushort4 o4;
            o4.x = f2bf(oA[t][0] * invA); o4.y = f2bf(oA[t][1] * invA);
            o4.z = f2bf(oA[t][2] * invA); o4.w = f2bf(oA[t][3] * invA);
            *(ushort4*)(Orow + t * 16 + quad * 4) = o4;
        }
    }
    {
        const int n = qwB + l16;
        unsigned short* Orow = O + ((size_t)(bb * NSEQ + n)) * 512 + h * 64;
        #pragma unroll
        for (int t = 0; t < 4; ++t) {
            ushort4 o4;
            o4.x = f2bf(oB[t][0] * invB); o4.y = f2bf(oB[t][1] * invB);
            o4.z = f2bf(oB[t][2] * invB); o4.w = f2bf(oB[t][3] * invB);
            *(ushort4*)(Orow + t * 16 + quad * 4) = o4;
        }
    }
}

extern "C" void kernel_launch(void* const* d_in, const int* in_sizes, int n_in,
                              void* d_out, int out_size, void* d_ws, size_t ws_size,
                              hipStream_t stream) {
    const float* x         = (const float*)d_in[0];
    const float* w_qkv     = (const float*)d_in[1];
    const float* w_out     = (const float*)d_in[2];
    const float* b_out     = (const float*)d_in[3];
    const float* log_scale = (const float*)d_in[4];
    float* out = (float*)d_out;

    char* ws = (char*)d_ws;
    const size_t NQKV = (size_t)NB * HEADS * NSEQ * DHEAD;        // 8,388,608 elems
    unsigned short* xb  = (unsigned short*)(ws);
    unsigned short* Qb  = (unsigned short*)(ws + 2 * NQKV);
    unsigned short* Kb  = (unsigned short*)(ws + 4 * NQKV);
    unsigned short* VTb = (unsigned short*)(ws + 6 * NQKV);
    unsigned short* Ofb = (unsigned short*)(ws + 8 * NQKV);
    unsigned short* WqT = (unsigned short*)(ws + 10 * NQKV);
    unsigned short* WoT = (unsigned short*)(ws + 10 * NQKV + 4 * 1024 * 1024);

    f32_to_bf16<<<M_TOT * DIMK / (256 * 8), 256, 0, stream>>>(x, xb);
    transpose_both<<<dim3(64, 16), 256, 0, stream>>>(w_qkv, w_out, WqT, WoT, log_scale);

    gemm_qkv_mfma<<<dim3(M_TOT / 128, 1536 / 128), 256, 0, stream>>>(xb, WqT, Qb, Kb, VTb);

    attn_mfma<<<dim3(NB * HEADS, NSEQ / 128), 256, 0, stream>>>(Qb, Kb, VTb, Ofb);

    gemm_out_mfma<<<dim3(M_TOT / 128, 512 / 128), 256, 0, stream>>>(Ofb, WoT, b_out, out);
}